// Round 12
// baseline (320.545 us; speedup 1.0000x reference)
//
#include <hip/hip_runtime.h>
#include <hip/hip_bf16.h>

// CrossNetMoE fully fused, BT=64 rows/WG, 1024 threads (16 waves), grid=256,
// all 3 layers in one kernel. L=3, E=4, D=1024, R=64, B=16384.
// LDS 160KB: s_xl [64][1024] f16 swizzled (128KB) + s_v [64][256] f16 (32KB).
// R12 = R10 + __launch_bounds__(1024, 1). Allocator model fitted over
// R5-R11: compiler sizes VGPRs for 2 resident blocks by default (1024thr ->
// 64-reg cap -> R9/R10 spilled); 2nd arg acts as CUDA min-blocks. (1024,1)
// -> cap 2048/16 = 128 regs/wave at 16 waves/CU = 4 waves/SIMD (2x TLP vs
// R8/R11). R10's phase layout was built to fit 128 (G3: 2 passes x 2
// n-tiles, peak live ~100 regs) -- so this isolates the launch-bounds fix.
// Tripwires: VGPR=64 or WRITE>100MB => model wrong, pivot to LDS staging.
// Gate: every wave computes the Wg-tile MFMA redundantly, softmax via
// shfl_xor over lanes 0-3, shfl broadcast of own expert's g.
// MFMA 16x16x32_f16; A/B frag k = 8*(lane>>4)+j; D: col=lane&15,
// row=4*(lane>>4)+reg [learn_hip m89].

typedef _Float16 f16;
typedef f16  f16x8 __attribute__((ext_vector_type(8)));
typedef float f32x4 __attribute__((ext_vector_type(4)));

#define B_TOT 16384
#define DDIM  1024
#define RLOW  64
#define NEXP  4
#define NLAY  3
#define BT    64

__device__ __forceinline__ float ftanh(float x) {
    float e2 = __expf(2.0f * x);          // inf-safe: ->1 / ->-1
    return 1.0f - 2.0f / (e2 + 1.0f);
}
__device__ __forceinline__ f32x4 mfma16(f16x8 a, f16x8 b, f32x4 c) {
    return __builtin_amdgcn_mfma_f32_16x16x32_f16(a, b, c, 0, 0, 0);
}
// swizzled byte offsets: row-stride 2048B (s_xl) / 512B (s_v); XOR bits 4-6
__device__ __forceinline__ int xl_off(int row, int col) {
    return row * 2048 + ((col * 2) ^ ((row & 7) << 4));
}
__device__ __forceinline__ int sv_off(int row, int col) {
    return row * 512 + ((col * 2) ^ ((row & 7) << 4));
}

__global__ void cast_f32_to_f16(const float* __restrict__ in,
                                f16* __restrict__ out, int n4) {
    int i = blockIdx.x * 256 + threadIdx.x;
    if (i < n4) {
        float4 v = reinterpret_cast<const float4*>(in)[i];
        f16 h0 = (f16)v.x, h1 = (f16)v.y, h2 = (f16)v.z, h3 = (f16)v.w;
        short4 pk;
        pk.x = __builtin_bit_cast(short, h0); pk.y = __builtin_bit_cast(short, h1);
        pk.z = __builtin_bit_cast(short, h2); pk.w = __builtin_bit_cast(short, h3);
        reinterpret_cast<short4*>(out)[i] = pk;
    }
}

// Wgh[l][16][1024] f16: rows 0-3 = Wg experts, rows 4-15 = 0.
__global__ void build_wgh(const float* __restrict__ Wg, f16* __restrict__ Wgh) {
    int i = blockIdx.x * 256 + threadIdx.x;          // < 3*16*1024
    int l = i >> 14, r = (i >> 10) & 15, k = i & 1023;
    f16 v = (f16)0.f;
    if (r < NEXP) v = (f16)Wg[(size_t)(l * NEXP + r) * DDIM + k];
    Wgh[i] = v;
}

__global__ __launch_bounds__(1024, 1) void crossnet_fused(
    const float* __restrict__ x, float* __restrict__ out,
    const f16* __restrict__ Uh,   // [L][E][D][R]
    const f16* __restrict__ Vh,   // [L][256][1024]
    const f16* __restrict__ Ch,   // [L][E][64][64]
    const f16* __restrict__ Wgh,  // [L][16][1024]
    const float* __restrict__ bias)  // [L][1024]
{
    __shared__ f16 s_xl[BT * 1024];   // 128 KB, swizzled
    __shared__ f16 s_v[BT * 256];     //  32 KB, swizzled (v then p)

    const int tid  = threadIdx.x;
    const int lane = tid & 63;
    const int wv   = tid >> 6;        // 0..15
    const int l16  = lane & 15;
    const int lhi  = lane >> 4;       // 0..3
    const int row0 = blockIdx.x * BT;
    const int eown = wv >> 2;         // this wave's expert for GEMM-2
    const int qown = wv & 3;          // col-quarter within expert

    // ---- stage x -> s_xl (f16, swizzled): 64 rows x 1024 cols
#pragma unroll
    for (int j = 0; j < 8; ++j) {
        int f = tid + j * 1024;       // 0..8191
        int row = f >> 7, seg = f & 127;
        const float4* sp = reinterpret_cast<const float4*>(
            x + (size_t)(row0 + row) * DDIM + seg * 8);
        float4 a = sp[0], b = sp[1];
        f16x8 h;
        h[0]=(f16)a.x; h[1]=(f16)a.y; h[2]=(f16)a.z; h[3]=(f16)a.w;
        h[4]=(f16)b.x; h[5]=(f16)b.y; h[6]=(f16)b.z; h[7]=(f16)b.w;
        *reinterpret_cast<f16x8*>((char*)s_xl + xl_off(row, seg * 8)) = h;
    }

#pragma unroll 1
    for (int l = 0; l < NLAY; ++l) {
        const f16* Vl = Vh  + (size_t)l * 256 * DDIM;
        const f16* Ul = Uh  + (size_t)l * NEXP * DDIM * RLOW;
        const f16* Cl = Ch  + (size_t)l * NEXP * RLOW * RLOW;
        const f16* Wl = Wgh + (size_t)l * 16 * DDIM;
        const float* bl = bias + (size_t)l * DDIM;
        const int last = (l == NLAY - 1);

        __syncthreads();   // s_xl ready; prev-layer s_v reads done

        // ===== GEMM-1: v = tanh(xl @ V^T); wave owns n-tile wv (16 tiles);
        //       gate logits computed redundantly by every wave.
        const f16* B0 = Vl + (size_t)(wv * 16 + l16) * DDIM + lhi * 8;
        const f16* BG = Wl + (size_t)l16 * DDIM + lhi * 8;
        f32x4 a0[4], ag[4];
#pragma unroll
        for (int mt = 0; mt < 4; ++mt) {
            a0[mt] = (f32x4){0.f,0.f,0.f,0.f};
            ag[mt] = (f32x4){0.f,0.f,0.f,0.f};
        }
#pragma unroll 2
        for (int kt = 0; kt < 32; ++kt) {
            f16x8 b0 = *reinterpret_cast<const f16x8*>(B0 + kt * 32);
            f16x8 bg = *reinterpret_cast<const f16x8*>(BG + kt * 32);
#pragma unroll
            for (int mt = 0; mt < 4; ++mt) {
                f16x8 af = *reinterpret_cast<const f16x8*>(
                    (char*)s_xl + xl_off(mt * 16 + l16, kt * 32 + lhi * 8));
                a0[mt] = mfma16(af, b0, a0[mt]);
                ag[mt] = mfma16(af, bg, ag[mt]);
            }
        }

        // gate softmax in-wave: logit[mt*16+4*lhi+r][e=l16<4] in ag[mt][r].
        float gmy[4][4];
#pragma unroll
        for (int mt = 0; mt < 4; ++mt)
#pragma unroll
            for (int r = 0; r < 4; ++r) {
                float lg = ag[mt][r];
                float mx = fmaxf(lg, __shfl_xor(lg, 1));
                mx = fmaxf(mx, __shfl_xor(mx, 2));
                float ex = __expf(lg - mx);
                float sm = ex;
                sm += __shfl_xor(sm, 1);
                sm += __shfl_xor(sm, 2);
                float gv = ex / sm;
                gmy[mt][r] = __shfl(gv, (lane & 48) | eown);
            }

        // write v (cols wv*16 + l16)
#pragma unroll
        for (int mt = 0; mt < 4; ++mt)
#pragma unroll
            for (int r = 0; r < 4; ++r) {
                const int row = mt * 16 + lhi * 4 + r;
                *reinterpret_cast<f16*>((char*)s_v + sv_off(row, wv * 16 + l16)) =
                    (f16)ftanh(a0[mt][r]);
            }

        __syncthreads();   // barrier-1: v complete

        // ===== GEMM-2: p = g * tanh(C_e @ v); wave -> expert eown, quarter qown
        f16x8 caf[4][2];   // [mt][kt2]
#pragma unroll
        for (int mt = 0; mt < 4; ++mt)
#pragma unroll
            for (int kt2 = 0; kt2 < 2; ++kt2)
                caf[mt][kt2] = *reinterpret_cast<const f16x8*>(
                    (char*)s_v + sv_off(mt * 16 + l16, eown * 64 + kt2 * 32 + lhi * 8));

        __syncthreads();   // barrier-2a: all v reads done

        {
            f32x4 c2[4];
#pragma unroll
            for (int mt = 0; mt < 4; ++mt) c2[mt] = (f32x4){0.f,0.f,0.f,0.f};
            const f16* CB0 = Cl + (size_t)(eown * 64 + qown * 16 + l16) * RLOW + lhi * 8;
#pragma unroll
            for (int kt2 = 0; kt2 < 2; ++kt2) {
                f16x8 cb = *reinterpret_cast<const f16x8*>(CB0 + kt2 * 32);
#pragma unroll
                for (int mt = 0; mt < 4; ++mt)
                    c2[mt] = mfma16(caf[mt][kt2], cb, c2[mt]);
            }
            // p = g * tanh(c); col = eown*64 + qown*16 + l16
#pragma unroll
            for (int mt = 0; mt < 4; ++mt)
#pragma unroll
                for (int r = 0; r < 4; ++r) {
                    const int row = mt * 16 + lhi * 4 + r;
                    const int col = eown * 64 + qown * 16 + l16;
                    *reinterpret_cast<f16*>((char*)s_v + sv_off(row, col)) =
                        (f16)(ftanh(c2[mt][r]) * gmy[mt][r]);
                }
        }

        __syncthreads();   // barrier-2: p complete

        // ===== GEMM-3: out = p @ U^T; wave owns d in [wv*64, +64),
        //       2 passes x 2 n-tiles (c3[4][2]=32 accs -> fits 128-reg budget)
#pragma unroll 1
        for (int ps = 0; ps < 2; ++ps) {
            const int dbase = wv * 64 + ps * 32;
            f32x4 c3[4][2];   // [mt][nt]
#pragma unroll
            for (int mt = 0; mt < 4; ++mt)
#pragma unroll
                for (int nt = 0; nt < 2; ++nt) c3[mt][nt] = (f32x4){0.f,0.f,0.f,0.f};
            float br[2];
#pragma unroll
            for (int nt = 0; nt < 2; ++nt) br[nt] = bl[dbase + nt * 16 + l16];
#pragma unroll 2
            for (int kt = 0; kt < 8; ++kt) {
                const size_t ebase = (size_t)(kt >> 1) * DDIM * RLOW + (kt & 1) * 32 + lhi * 8;
                f16x8 af[4];
#pragma unroll
                for (int mt = 0; mt < 4; ++mt)
                    af[mt] = *reinterpret_cast<const f16x8*>(
                        (char*)s_v + sv_off(mt * 16 + l16, kt * 32 + lhi * 8));
#pragma unroll
                for (int nt = 0; nt < 2; ++nt) {
                    const f16* ub = Ul + ebase + (size_t)(dbase + nt * 16 + l16) * RLOW;
                    f16x8 bf = *reinterpret_cast<const f16x8*>(ub);
#pragma unroll
                    for (int mt = 0; mt < 4; ++mt)
                        c3[mt][nt] = mfma16(af[mt], bf, c3[mt][nt]);
                }
            }
            // epilogue: y = (u+b)*x0 + xl ; xl' = tanh(y) (layers 0,1)
#pragma unroll
            for (int nt = 0; nt < 2; ++nt) {
                const int d = dbase + nt * 16 + l16;
#pragma unroll
                for (int mt = 0; mt < 4; ++mt)
#pragma unroll
                    for (int r = 0; r < 4; ++r) {
                        const int m = mt * 16 + lhi * 4 + r;
                        const float x0f = x[(size_t)(row0 + m) * DDIM + d];
                        const float xlf = (float)*reinterpret_cast<const f16*>(
                            (char*)s_xl + xl_off(m, d));
                        float y = fmaf(c3[mt][nt][r] + br[nt], x0f, xlf);
                        if (!last)
                            *reinterpret_cast<f16*>((char*)s_xl + xl_off(m, d)) = (f16)ftanh(y);
                        else
                            __builtin_nontemporal_store(y, out + (size_t)(row0 + m) * DDIM + d);
                    }
            }
        }
    }
}

extern "C" void kernel_launch(void* const* d_in, const int* in_sizes, int n_in,
                              void* d_out, int out_size, void* d_ws, size_t ws_size,
                              hipStream_t stream)
{
    const float* x  = (const float*)d_in[0];
    const float* U  = (const float*)d_in[1];
    const float* V  = (const float*)d_in[2];
    const float* C  = (const float*)d_in[3];
    const float* Wg = (const float*)d_in[4];
    const float* bb = (const float*)d_in[5];
    float* out = (float*)d_out;

    const size_t sUV = (size_t)NEXP * DDIM * RLOW;          // 262144 per layer
    const size_t sC  = (size_t)NEXP * RLOW * RLOW;          // 16384  per layer
    const size_t sW  = (size_t)16 * DDIM;                   // 16384  per layer

    f16* Vh  = (f16*)d_ws;                                  // 1.5 MB
    f16* Uh  = Vh + NLAY * sUV;                             // 1.5 MB
    f16* Chh = Uh + NLAY * sUV;                             // 96 KB
    f16* Wgh = Chh + NLAY * sC;                             // 96 KB

    int n4v = (int)(NLAY * sUV / 4);
    cast_f32_to_f16<<<(n4v + 255) / 256, 256, 0, stream>>>(V, Vh, n4v);
    cast_f32_to_f16<<<(n4v + 255) / 256, 256, 0, stream>>>(U, Uh, n4v);
    int n4c = (int)(NLAY * sC / 4);
    cast_f32_to_f16<<<(n4c + 255) / 256, 256, 0, stream>>>(C, Chh, n4c);
    build_wgh<<<(int)(NLAY * sW / 256), 256, 0, stream>>>(Wg, Wgh);

    crossnet_fused<<<dim3(B_TOT / BT), dim3(1024), 0, stream>>>(
        x, out, Uh, Vh, Chh, Wgh, bb);
}

// Round 13
// 195.971 us; speedup vs baseline: 1.6357x; 1.6357x over previous
//
#include <hip/hip_runtime.h>
#include <hip/hip_bf16.h>

// CrossNetMoE fully fused, BT=64 rows/WG, 512 threads, grid=256 (1 WG/CU),
// all 3 layers in one kernel. L=3, E=4, D=1024, R=64, B=16384.
// LDS 160KB: s_xl [64][1024] f16 swizzled (128KB) + s_v [64][256] f16 (32KB).
// R13 = R11 shell + OPERAND-SWAP VECTORIZATION: mfma16(weight_frag, xl_frag)
// transposes the D-tile (slot-1 -> (lhi,r) row axis, slot-2 -> l16 col axis;
// fragment addressing identical in both slots). Each lane then holds 4
// CONSECUTIVE n/d outputs for one row m=l16 -> v/p writes become
// ds_write_b64, epilogue becomes ds_read_b64 + float4 x0 load + float4
// store (4x fewer memory instructions), gate softmax becomes lane-local
// (logits [e=4lhi+r][m=l16]) with one shfl broadcast per m-tile.
// Launch-bounds lore (R5-R12): 512thr+(512,1) -> VGPR cap 128, no spill;
// any 1024-thr config -> 64-reg cap + spill catastrophe. Stay at (512,1).
// MFMA 16x16x32_f16; frag k = 8*(lane>>4)+j; D: col=lane&15 (slot-2 axis),
// row=4*(lane>>4)+reg (slot-1 axis) [learn_hip m89].

typedef _Float16 f16;
typedef f16  f16x4v __attribute__((ext_vector_type(4)));
typedef f16  f16x8 __attribute__((ext_vector_type(8)));
typedef float f32x4 __attribute__((ext_vector_type(4)));

#define B_TOT 16384
#define DDIM  1024
#define RLOW  64
#define NEXP  4
#define NLAY  3
#define BT    64

__device__ __forceinline__ float ftanh(float x) {
    float e2 = __expf(2.0f * x);          // inf-safe: ->1 / ->-1
    return 1.0f - 2.0f / (e2 + 1.0f);
}
__device__ __forceinline__ f32x4 mfma16(f16x8 a, f16x8 b, f32x4 c) {
    return __builtin_amdgcn_mfma_f32_16x16x32_f16(a, b, c, 0, 0, 0);
}
// swizzled byte offsets: row-stride 2048B (s_xl) / 512B (s_v); XOR bits 4-6
__device__ __forceinline__ int xl_off(int row, int col) {
    return row * 2048 + ((col * 2) ^ ((row & 7) << 4));
}
__device__ __forceinline__ int sv_off(int row, int col) {
    return row * 512 + ((col * 2) ^ ((row & 7) << 4));
}

__global__ void cast_f32_to_f16(const float* __restrict__ in,
                                f16* __restrict__ out, int n4) {
    int i = blockIdx.x * 256 + threadIdx.x;
    if (i < n4) {
        float4 v = reinterpret_cast<const float4*>(in)[i];
        f16 h0 = (f16)v.x, h1 = (f16)v.y, h2 = (f16)v.z, h3 = (f16)v.w;
        short4 pk;
        pk.x = __builtin_bit_cast(short, h0); pk.y = __builtin_bit_cast(short, h1);
        pk.z = __builtin_bit_cast(short, h2); pk.w = __builtin_bit_cast(short, h3);
        reinterpret_cast<short4*>(out)[i] = pk;
    }
}

// Wgh[l][16][1024] f16: rows 0-3 = Wg experts, rows 4-15 = 0.
__global__ void build_wgh(const float* __restrict__ Wg, f16* __restrict__ Wgh) {
    int i = blockIdx.x * 256 + threadIdx.x;          // < 3*16*1024
    int l = i >> 14, r = (i >> 10) & 15, k = i & 1023;
    f16 v = (f16)0.f;
    if (r < NEXP) v = (f16)Wg[(size_t)(l * NEXP + r) * DDIM + k];
    Wgh[i] = v;
}

__global__ __launch_bounds__(512, 1) void crossnet_fused(
    const float* __restrict__ x, float* __restrict__ out,
    const f16* __restrict__ Uh,   // [L][E][D][R]
    const f16* __restrict__ Vh,   // [L][256][1024]
    const f16* __restrict__ Ch,   // [L][E][64][64]
    const f16* __restrict__ Wgh,  // [L][16][1024]
    const float* __restrict__ bias)  // [L][1024]
{
    __shared__ f16 s_xl[BT * 1024];   // 128 KB, swizzled
    __shared__ f16 s_v[BT * 256];     //  32 KB, swizzled (v then p)

    const int tid  = threadIdx.x;
    const int lane = tid & 63;
    const int wv   = tid >> 6;        // 0..7
    const int l16  = lane & 15;
    const int lhi  = lane >> 4;       // 0..3
    const int row0 = blockIdx.x * BT;
    const int eown = wv >> 1;         // this wave's expert for GEMM-2
    const int hown = wv & 1;

    // ---- stage x -> s_xl (f16, swizzled): 64 rows x 1024 cols
#pragma unroll
    for (int j = 0; j < 16; ++j) {
        int f = tid + j * 512;        // 0..8191
        int row = f >> 7, seg = f & 127;
        const float4* sp = reinterpret_cast<const float4*>(
            x + (size_t)(row0 + row) * DDIM + seg * 8);
        float4 a = sp[0], b = sp[1];
        f16x8 h;
        h[0]=(f16)a.x; h[1]=(f16)a.y; h[2]=(f16)a.z; h[3]=(f16)a.w;
        h[4]=(f16)b.x; h[5]=(f16)b.y; h[6]=(f16)b.z; h[7]=(f16)b.w;
        *reinterpret_cast<f16x8*>((char*)s_xl + xl_off(row, seg * 8)) = h;
    }

#pragma unroll 1
    for (int l = 0; l < NLAY; ++l) {
        const f16* Vl = Vh  + (size_t)l * 256 * DDIM;
        const f16* Ul = Uh  + (size_t)l * NEXP * DDIM * RLOW;
        const f16* Cl = Ch  + (size_t)l * NEXP * RLOW * RLOW;
        const f16* Wl = Wgh + (size_t)l * 16 * DDIM;
        const float* bl = bias + (size_t)l * DDIM;
        const int last = (l == NLAY - 1);

        __syncthreads();   // s_xl ready; prev-layer s_v reads done

        // ===== GEMM-1: v = tanh(xl @ V^T); wave owns n-tiles {2wv, 2wv+1};
        //       gate logits redundantly per wave. Swapped operands:
        //       D row(4lhi+r)=n-in-tile, col(l16)=m.
        const f16* B0 = Vl + (size_t)(2 * wv * 16 + l16) * DDIM + lhi * 8;
        const f16* B1 = Vl + (size_t)((2 * wv + 1) * 16 + l16) * DDIM + lhi * 8;
        const f16* BG = Wl + (size_t)l16 * DDIM + lhi * 8;
        f32x4 a0[4], a1[4], ag[4];
#pragma unroll
        for (int mt = 0; mt < 4; ++mt) {
            a0[mt] = (f32x4){0.f,0.f,0.f,0.f};
            a1[mt] = (f32x4){0.f,0.f,0.f,0.f};
            ag[mt] = (f32x4){0.f,0.f,0.f,0.f};
        }
#pragma unroll 4
        for (int kt = 0; kt < 32; ++kt) {
            f16x8 b0 = *reinterpret_cast<const f16x8*>(B0 + kt * 32);
            f16x8 b1 = *reinterpret_cast<const f16x8*>(B1 + kt * 32);
            f16x8 bg = *reinterpret_cast<const f16x8*>(BG + kt * 32);
#pragma unroll
            for (int mt = 0; mt < 4; ++mt) {
                f16x8 af = *reinterpret_cast<const f16x8*>(
                    (char*)s_xl + xl_off(mt * 16 + l16, kt * 32 + lhi * 8));
                a0[mt] = mfma16(b0, af, a0[mt]);
                a1[mt] = mfma16(b1, af, a1[mt]);
                ag[mt] = mfma16(bg, af, ag[mt]);
            }
        }

        // gate softmax: ag[mt] holds logits[e=4*lhi+r][m=mt*16+l16]; lanes
        // lhi==0 own e=0..3 locally -> lane-local softmax, shfl broadcast.
        float gmy[4];
#pragma unroll
        for (int mt = 0; mt < 4; ++mt) {
            float e0 = ag[mt][0], e1 = ag[mt][1], e2 = ag[mt][2], e3 = ag[mt][3];
            float mx = fmaxf(fmaxf(e0, e1), fmaxf(e2, e3));
            float x0e = __expf(e0 - mx), x1e = __expf(e1 - mx);
            float x2e = __expf(e2 - mx), x3e = __expf(e3 - mx);
            float inv = 1.0f / (x0e + x1e + x2e + x3e);
            float ge = (eown == 0) ? x0e : (eown == 1) ? x1e : (eown == 2) ? x2e : x3e;
            gmy[mt] = __shfl(ge * inv, l16);   // from the lhi==0 lane owning m
        }

        // write v: per (tile, mt) 4 consecutive n -> one ds_write_b64
#pragma unroll
        for (int mt = 0; mt < 4; ++mt) {
            const int m = mt * 16 + l16;
            f16x4v w0, w1;
#pragma unroll
            for (int r = 0; r < 4; ++r) {
                w0[r] = (f16)ftanh(a0[mt][r]);
                w1[r] = (f16)ftanh(a1[mt][r]);
            }
            *reinterpret_cast<f16x4v*>((char*)s_v + sv_off(m, (2 * wv) * 16 + lhi * 4))     = w0;
            *reinterpret_cast<f16x4v*>((char*)s_v + sv_off(m, (2 * wv + 1) * 16 + lhi * 4)) = w1;
        }

        __syncthreads();   // barrier-1: v complete

        // ===== GEMM-2: p = g * tanh(C_e @ v); wave -> expert eown, half hown
        f16x8 caf[4][2];   // [mt][kt2]  (A-role frags, slot-2)
#pragma unroll
        for (int mt = 0; mt < 4; ++mt)
#pragma unroll
            for (int kt2 = 0; kt2 < 2; ++kt2)
                caf[mt][kt2] = *reinterpret_cast<const f16x8*>(
                    (char*)s_v + sv_off(mt * 16 + l16, eown * 64 + kt2 * 32 + lhi * 8));

        __syncthreads();   // barrier-2a: all v reads done

        {
            f32x4 c2[4][2];
#pragma unroll
            for (int mt = 0; mt < 4; ++mt) {
                c2[mt][0] = (f32x4){0.f,0.f,0.f,0.f};
                c2[mt][1] = (f32x4){0.f,0.f,0.f,0.f};
            }
            const f16* CB0 = Cl + (size_t)(eown * 64 + hown * 32 + l16) * RLOW + lhi * 8;
            const f16* CB1 = CB0 + 16 * RLOW;
#pragma unroll
            for (int kt2 = 0; kt2 < 2; ++kt2) {
                f16x8 cb0 = *reinterpret_cast<const f16x8*>(CB0 + kt2 * 32);
                f16x8 cb1 = *reinterpret_cast<const f16x8*>(CB1 + kt2 * 32);
#pragma unroll
                for (int mt = 0; mt < 4; ++mt) {
                    c2[mt][0] = mfma16(cb0, caf[mt][kt2], c2[mt][0]);
                    c2[mt][1] = mfma16(cb1, caf[mt][kt2], c2[mt][1]);
                }
            }
            // p = g * tanh(c); per (mt, ntc) 4 consecutive cols -> ds_write_b64
#pragma unroll
            for (int mt = 0; mt < 4; ++mt) {
                const int m = mt * 16 + l16;
#pragma unroll
                for (int ntc = 0; ntc < 2; ++ntc) {
                    f16x4v w;
#pragma unroll
                    for (int r = 0; r < 4; ++r)
                        w[r] = (f16)(ftanh(c2[mt][ntc][r]) * gmy[mt]);
                    const int col = eown * 64 + hown * 32 + ntc * 16 + lhi * 4;
                    *reinterpret_cast<f16x4v*>((char*)s_v + sv_off(m, col)) = w;
                }
            }
        }

        __syncthreads();   // barrier-2: p complete

        // ===== GEMM-3: out = p @ U^T; wave owns d in [wv*128, +128), 2 passes.
        //       Swapped: acc[dt][mt] row(4lhi+r)=d-in-tile, col(l16)=m.
#pragma unroll 1
        for (int ps = 0; ps < 2; ++ps) {
            const int dbase = wv * 128 + ps * 64;
            f32x4 c3[4][4];   // [dt][mt]
#pragma unroll
            for (int dt = 0; dt < 4; ++dt)
#pragma unroll
                for (int mt = 0; mt < 4; ++mt) c3[dt][mt] = (f32x4){0.f,0.f,0.f,0.f};
#pragma unroll 4
            for (int kt = 0; kt < 8; ++kt) {
                const size_t ebase = (size_t)(kt >> 1) * DDIM * RLOW + (kt & 1) * 32 + lhi * 8;
                f16x8 af[4];
#pragma unroll
                for (int mt = 0; mt < 4; ++mt)
                    af[mt] = *reinterpret_cast<const f16x8*>(
                        (char*)s_v + sv_off(mt * 16 + l16, kt * 32 + lhi * 8));
#pragma unroll
                for (int dt = 0; dt < 4; ++dt) {
                    const f16* ub = Ul + ebase + (size_t)(dbase + dt * 16 + l16) * RLOW;
                    f16x8 bf = *reinterpret_cast<const f16x8*>(ub);
#pragma unroll
                    for (int mt = 0; mt < 4; ++mt)
                        c3[dt][mt] = mfma16(bf, af[mt], c3[dt][mt]);
                }
            }
            // epilogue (vectorized): per (dt,mt): d0..d0+3 for one row m
            f32x4 biasv[4];
#pragma unroll
            for (int dt = 0; dt < 4; ++dt)
                biasv[dt] = *reinterpret_cast<const f32x4*>(bl + dbase + dt * 16 + lhi * 4);
#pragma unroll
            for (int dt = 0; dt < 4; ++dt) {
                const int d0 = dbase + dt * 16 + lhi * 4;
#pragma unroll
                for (int mt = 0; mt < 4; ++mt) {
                    const int m = mt * 16 + l16;
                    f32x4 x0v = *reinterpret_cast<const f32x4*>(
                        x + (size_t)(row0 + m) * DDIM + d0);
                    f32x4 xlv;
                    if (l == 0) {
                        xlv = x0v;                          // layer 0: xl == x0 (f32)
                    } else {
                        f16x4v h = *reinterpret_cast<const f16x4v*>(
                            (char*)s_xl + xl_off(m, d0));
                        xlv[0] = (float)h[0]; xlv[1] = (float)h[1];
                        xlv[2] = (float)h[2]; xlv[3] = (float)h[3];
                    }
                    f32x4 y;
#pragma unroll
                    for (int r = 0; r < 4; ++r)
                        y[r] = fmaf(c3[dt][mt][r] + biasv[dt][r], x0v[r], xlv[r]);
                    if (!last) {
                        f16x4v hw;
#pragma unroll
                        for (int r = 0; r < 4; ++r) hw[r] = (f16)ftanh(y[r]);
                        *reinterpret_cast<f16x4v*>((char*)s_xl + xl_off(m, d0)) = hw;
                    } else {
                        __builtin_nontemporal_store(y,
                            reinterpret_cast<f32x4*>(out + (size_t)(row0 + m) * DDIM + d0));
                    }
                }
            }
        }
    }
}

extern "C" void kernel_launch(void* const* d_in, const int* in_sizes, int n_in,
                              void* d_out, int out_size, void* d_ws, size_t ws_size,
                              hipStream_t stream)
{
    const float* x  = (const float*)d_in[0];
    const float* U  = (const float*)d_in[1];
    const float* V  = (const float*)d_in[2];
    const float* C  = (const float*)d_in[3];
    const float* Wg = (const float*)d_in[4];
    const float* bb = (const float*)d_in[5];
    float* out = (float*)d_out;

    const size_t sUV = (size_t)NEXP * DDIM * RLOW;          // 262144 per layer
    const size_t sC  = (size_t)NEXP * RLOW * RLOW;          // 16384  per layer
    const size_t sW  = (size_t)16 * DDIM;                   // 16384  per layer

    f16* Vh  = (f16*)d_ws;                                  // 1.5 MB
    f16* Uh  = Vh + NLAY * sUV;                             // 1.5 MB
    f16* Chh = Uh + NLAY * sUV;                             // 96 KB
    f16* Wgh = Chh + NLAY * sC;                             // 96 KB

    int n4v = (int)(NLAY * sUV / 4);
    cast_f32_to_f16<<<(n4v + 255) / 256, 256, 0, stream>>>(V, Vh, n4v);
    cast_f32_to_f16<<<(n4v + 255) / 256, 256, 0, stream>>>(U, Uh, n4v);
    int n4c = (int)(NLAY * sC / 4);
    cast_f32_to_f16<<<(n4c + 255) / 256, 256, 0, stream>>>(C, Chh, n4c);
    build_wgh<<<(int)(NLAY * sW / 256), 256, 0, stream>>>(Wg, Wgh);

    crossnet_fused<<<dim3(B_TOT / BT), dim3(512), 0, stream>>>(
        x, out, Uh, Vh, Chh, Wgh, bb);
}